// Round 10
// baseline (2735.327 us; speedup 1.0000x reference)
//
#include <hip/hip_runtime.h>
#include <hip/hip_bf16.h>

// ---- problem sizes ----
#define UNITS 1024
#define FEATS 128
#define NG    4096
#define NSTEP 383            // 256 warmup + 127 forecast
#define HS    262144         // elems per h slice (256*1024)
#define HSB   524288UL       // bytes per h slice

// ---- ws offsets (bytes) ----
#define OX   0UL             // x bf16 [256][256][128]          16,777,216  (hist 1..32)
#define OWH  16777216UL      // WhR [4096][1024] bf16            8,388,608  (hist 33..48)
#define OWI  25165824UL      // WiR [4096][128] bf16             1,048,576  (hist 49..50)
#define OWF  26214400UL      // WfR [4096][1024] bf16            8,388,608  (hist 112..127)
#define OWD  34603008UL      // WdT [128][1024] bf16               262,144
#define OBR  34865152UL      // bias_r [4096] f32                   16,384
#define OBF  34881536UL      // bias_f [4096] f32                   16,384
#define OH0  34897920UL      // hist(0)                            524,288
#define OHP  35422208UL      // hp0, hp1                         1,048,576
#define OHC  36470784UL      // dedicated hist 51..111 (61)     31,981,568
#define OCNT 68452352UL      // flags[8 grp][2 g][8 c] x 64B = 8192
                             // +8192: agent slotc[8] (own line)
                             // +8320: agent global counter

typedef __attribute__((ext_vector_type(8))) short bf16x8;
typedef __attribute__((ext_vector_type(4))) float f32x4;
typedef __attribute__((ext_vector_type(4))) int i32x4;
typedef __attribute__((address_space(3))) char lds_char;
typedef __attribute__((address_space(1))) const char glb_char;

__device__ __forceinline__ void gload_lds16(const void* g, void* l) {
    __builtin_amdgcn_global_load_lds((glb_char*)g, (lds_char*)l, 16, 0, 0);
}
__device__ __forceinline__ int llc_load(const int* p) {
    int v;
    asm volatile("global_load_dword %0, %1, off sc0 sc1\n\ts_waitcnt vmcnt(0)"
                 : "=v"(v) : "v"(p) : "memory");
    return v;
}
__device__ __forceinline__ void l2_atomic_inc(int* p) {
    int one = 1;
    asm volatile("global_atomic_add %0, %1, off" :: "v"(p), "v"(one) : "memory");
}
__device__ __forceinline__ int l2_atomic_poll(int* p) {
    int v; int zero = 0;
    asm volatile("global_atomic_add %0, %1, %2, off sc0\n\ts_waitcnt vmcnt(0)"
                 : "=v"(v) : "v"(p), "v"(zero) : "memory");
    return v;
}

#define CFENCE asm volatile("" ::: "memory")
#define VMCNT0 asm volatile("s_waitcnt vmcnt(0)" ::: "memory")
#define L1INV  asm volatile("buffer_inv" ::: "memory")

__device__ __forceinline__ float sigf(float x) { return 1.0f / (1.0f + __expf(-x)); }
__device__ __forceinline__ float tanh_fast(float x) { return 2.0f / (1.0f + __expf(-2.0f * x)) - 1.0f; }

__device__ __forceinline__ int PK(int k) {
    return (k & ~15) | ((k & 3) << 2) | ((k >> 2) & 3);
}

__device__ __forceinline__ __hip_bfloat16* hist_ptr(char* ws, int s) {
    size_t off;
    if (s == 0)        off = OH0;
    else if (s <= 32)  off = OX  + (size_t)(s - 1) * HSB;
    else if (s <= 48)  off = OWH + (size_t)(s - 33) * HSB;
    else if (s <= 50)  off = OWI + (size_t)(s - 49) * HSB;
    else if (s <= 111) off = OHC + (size_t)(s - 51) * HSB;
    else               off = OWF + (size_t)(s - 112) * HSB;
    return (__hip_bfloat16*)(ws + off);
}

__device__ __forceinline__ void llc_sync(int* c, int target) {
    CFENCE;
    __syncthreads();
    if (threadIdx.x == 0) {
        atomicAdd(c, 1);
        while (llc_load(c) < target) __builtin_amdgcn_s_sleep(8);
    }
    __syncthreads();
    CFENCE;
}

// ---------- precompute kernels ----------

__global__ void cvt_bf16(const float* __restrict__ in, __hip_bfloat16* __restrict__ out, int n) {
    int i = (blockIdx.x * blockDim.x + threadIdx.x) * 4;
    if (i >= n) return;
    float4 v = *(const float4*)(in + i);
    union { ushort4 u4; __hip_bfloat16 h[4]; } pk;
    pk.h[0] = __float2bfloat16(v.x);
    pk.h[1] = __float2bfloat16(v.y);
    pk.h[2] = __float2bfloat16(v.z);
    pk.h[3] = __float2bfloat16(v.w);
    *(ushort4*)(out + i) = pk.u4;
}

__global__ void build_whwi(const float* __restrict__ Wh, const float* __restrict__ Wi,
                           __hip_bfloat16* __restrict__ WhR, __hip_bfloat16* __restrict__ WiR) {
    int idx = blockIdx.x * 256 + threadIdx.x;
    int k = idx >> 12, col = idx & 4095;
    int j = ((col & 1023) << 2) | (col >> 10);
    if (k < 1024) WhR[(size_t)j * 1024 + k] = __float2bfloat16(Wh[(size_t)PK(k) * 4096 + col]);
    else          WiR[(size_t)j * 128 + (k - 1024)] = __float2bfloat16(Wi[(size_t)(k - 1024) * 4096 + col]);
}

__global__ void build_wd(const float* __restrict__ Wd, __hip_bfloat16* __restrict__ WdT) {
    int idx = blockIdx.x * 256 + threadIdx.x;
    int f = idx >> 10, k = idx & 1023;
    WdT[(size_t)f * 1024 + k] = __float2bfloat16(Wd[(size_t)PK(k) * 128 + f]);
}

__global__ void build_bias(const float* __restrict__ b, const float* __restrict__ bd,
                           const float* __restrict__ Wi, float* __restrict__ br, float* __restrict__ bf) {
    int j = blockIdx.x * 256 + threadIdx.x;
    int col = ((j & 3) << 10) | (j >> 2);
    float base = b[col];
    br[j] = base;
    float v = base;
    for (int q = 0; q < 128; ++q) v += bd[q] * Wi[(size_t)q * 4096 + col];
    bf[j] = v;
}

__global__ __launch_bounds__(256) void build_wf(const __hip_bfloat16* __restrict__ WhR,
                                                const __hip_bfloat16* __restrict__ WiR,
                                                const float* __restrict__ Wd,
                                                __hip_bfloat16* __restrict__ WfR) {
    const int j0 = blockIdx.x * 64, k0 = blockIdx.y * 64;
    const int tid = threadIdx.x, wave = tid >> 6, lane = tid & 63;
    const int wj = (wave >> 1) * 32, wk = (wave & 1) * 32;
    const int lr = lane & 15, lq = lane >> 4;
    const int TL = ((lr & 3) << 2) | (lr >> 2);
    f32x4 acc[2][2] = {};
    #pragma unroll
    for (int kc = 0; kc < 4; ++kc) {
        bf16x8 dfr[2], ifr[2];
        #pragma unroll
        for (int q2 = 0; q2 < 2; ++q2) {
            const float* p = Wd + (size_t)(k0 + wk + q2 * 16 + TL) * 128 + kc * 32 + lq * 8;
            __hip_bfloat16* dp = (__hip_bfloat16*)&dfr[q2];
            #pragma unroll
            for (int e = 0; e < 8; ++e) dp[e] = __float2bfloat16(p[e]);
            ifr[q2] = *(const bf16x8*)(WiR + (size_t)(j0 + wj + q2 * 16 + lr) * 128 + kc * 32 + lq * 8);
        }
        acc[0][0] = __builtin_amdgcn_mfma_f32_16x16x32_bf16(dfr[0], ifr[0], acc[0][0], 0, 0, 0);
        acc[0][1] = __builtin_amdgcn_mfma_f32_16x16x32_bf16(dfr[0], ifr[1], acc[0][1], 0, 0, 0);
        acc[1][0] = __builtin_amdgcn_mfma_f32_16x16x32_bf16(dfr[1], ifr[0], acc[1][0], 0, 0, 0);
        acc[1][1] = __builtin_amdgcn_mfma_f32_16x16x32_bf16(dfr[1], ifr[1], acc[1][1], 0, 0, 0);
    }
    #pragma unroll
    for (int cf = 0; cf < 2; ++cf)
        #pragma unroll
        for (int rf = 0; rf < 2; ++rf) {
            const int k = k0 + wk + cf * 16 + lq * 4;
            const int j = j0 + wj + rf * 16 + lr;
            const __hip_bfloat16* whp = WhR + (size_t)j * 1024 + k;
            __hip_bfloat16* wfp = WfR + (size_t)j * 1024 + k;
            #pragma unroll
            for (int e = 0; e < 4; ++e)
                wfp[e] = __float2bfloat16(acc[cf][rf][e] + __bfloat162float(whp[e]));
        }
}

// ---------- persistent LSTM kernel: 2 independent 16-batch groups interleaved ----------
__global__ __launch_bounds__(512, 2) void persist(char* ws) {
    const __hip_bfloat16* xb  = (const __hip_bfloat16*)(ws + OX);
    const __hip_bfloat16* whg = (const __hip_bfloat16*)(ws + OWH);
    const __hip_bfloat16* wig = (const __hip_bfloat16*)(ws + OWI);
    const __hip_bfloat16* wfg = (const __hip_bfloat16*)(ws + OWF);
    const float* brg = (const float*)(ws + OBR);
    const float* bfg = (const float*)(ws + OBF);
    __hip_bfloat16* hp0 = (__hip_bfloat16*)(ws + OHP);
    __hip_bfloat16* hp1 = hp0 + HS;

    __shared__ __hip_bfloat16 Als[2][9][16][128];  // 73,728 B: per-group staging (x + 8 h chunks)
    __shared__ float Xl[4][2][4][256];             // 32,768 B: K-split exchange (shared by groups)
    __shared__ __hip_bfloat16 hTile[2][16][32];    //  2,048 B
    __shared__ int claimv[2];
    __shared__ int rdy[2][8];                      // per-group per-chunk-wave LDS ready (monotone)

    const int tid = threadIdx.x;

    if (tid < 16) rdy[tid >> 3][tid & 7] = 0;
    if (tid == 0) {
        unsigned xcd;
        asm volatile("s_getreg_b32 %0, hwreg(HW_REG_XCC_ID, 0, 32)" : "=s"(xcd));
        int* slotc = (int*)(ws + OCNT + 8192);
        int slot = atomicAdd(slotc + (xcd & 7), 1);
        claimv[0] = (int)(xcd & 7);
        claimv[1] = slot & 31;
    }
    __syncthreads();
    const int grp  = claimv[0];
    const int tile = claimv[1];
    const int n0 = tile * 128;
    const int b0 = grp * 32;
    const int ublk = tile * 32;
    int* fbase = (int*)(ws + OCNT + (size_t)grp * 1024);   // flag(g,c) at +(g*8+c)*64B
    int* glc   = (int*)(ws + OCNT + 8320);

    const int wave = tid >> 6, lane = tid & 63;
    const int cq = wave & 1, kh = wave >> 1;
    const int lr = lane & 15, lq = lane >> 4;

    // weights -> registers. w[tc][0]=Wi chunk; w[tc][1+c]=Wh chunk c (this wave's K-quarter).
    bf16x8 w[4][9];
    #pragma unroll
    for (int tc = 0; tc < 4; ++tc) {
        const size_t row = (size_t)(n0 + cq * 64 + tc * 16 + lr);
        w[tc][0] = *(const bf16x8*)(wig + row * 128 + kh * 32 + lq * 8);
        #pragma unroll
        for (int c = 0; c < 8; ++c)
            w[tc][1 + c] = *(const bf16x8*)(whg + row * 1024 + c * 128 + kh * 32 + lq * 8);
    }
    float4 biasq = *(const float4*)(brg + n0 + cq * 64 + kh * 16 + lq * 4);
    float creg[2] = {0.f, 0.f};   // per-group cell: unit cq*16+kh*4+lq, batch lr

    // stager geometry: 4 loads per 16x128 chunk; load j covers rows j*4+(lane>>4)
    const int sr = lane >> 4;            // 0..3
    const int scol = lane & 15;          // 16B chunk in row

    for (int t = 0; t < NSTEP; ++t) {
        const bool fc = (t >= 256);
        const __hip_bfloat16* hsrc = fc ? hist_ptr(ws, t - 256) : ((t & 1) ? hp1 : hp0);
        __hip_bfloat16* hdst = (t >= 255) ? hist_ptr(ws, t - 255) : ((t & 1) ? hp0 : hp1);

        if (t == 256) {
            #pragma unroll
            for (int tc = 0; tc < 4; ++tc) {
                const size_t row = (size_t)(n0 + cq * 64 + tc * 16 + lr);
                #pragma unroll
                for (int c = 0; c < 8; ++c)
                    w[tc][1 + c] = *(const bf16x8*)(wfg + row * 1024 + c * 128 + kh * 32 + lq * 8);
            }
            biasq = *(const float4*)(bfg + n0 + cq * 64 + kh * 16 + lq * 4);
            VMCNT0;
            llc_sync(glc, 256);
        }

        // ---- poll G0, stage G0; poll G1 (overlaps G0 latency), stage G1 ----
        if (t > 0 && lane == 0) {
            int* f0 = fbase + wave * 16;
            while (l2_atomic_poll(f0) < 4 * t) __builtin_amdgcn_s_sleep(1);
        }
        L1INV;
        {
            const int b0g = b0;
            if (!fc && wave == 0) {
                #pragma unroll
                for (int j = 0; j < 4; ++j) {
                    const int row = j * 4 + sr;
                    const int ce = (scol ^ row) << 3;
                    gload_lds16(xb + (size_t)(b0g + row) * 32768 + (size_t)t * 128 + ce,
                                (char*)&Als[0][0][0][0] + j * 1024);
                }
            }
            const __hip_bfloat16* srcb = hsrc + (size_t)b0g * 1024 + wave * 128;
            #pragma unroll
            for (int j = 0; j < 4; ++j) {
                const int row = j * 4 + sr;
                const int ce = (scol ^ row) << 3;
                gload_lds16(srcb + (size_t)row * 1024 + ce,
                            (char*)&Als[0][1 + wave][0][0] + j * 1024);
            }
        }
        if (t > 0 && lane == 0) {
            int* f1 = fbase + (8 + wave) * 16;
            while (l2_atomic_poll(f1) < 4 * t) __builtin_amdgcn_s_sleep(1);
        }
        {
            const int b0g = b0 + 16;
            if (!fc && wave == 0) {
                #pragma unroll
                for (int j = 0; j < 4; ++j) {
                    const int row = j * 4 + sr;
                    const int ce = (scol ^ row) << 3;
                    gload_lds16(xb + (size_t)(b0g + row) * 32768 + (size_t)t * 128 + ce,
                                (char*)&Als[1][0][0][0] + j * 1024);
                }
            }
            const __hip_bfloat16* srcb = hsrc + (size_t)b0g * 1024 + wave * 128;
            #pragma unroll
            for (int j = 0; j < 4; ++j) {
                const int row = j * 4 + sr;
                const int ce = (scol ^ row) << 3;
                gload_lds16(srcb + (size_t)row * 1024 + ce,
                            (char*)&Als[1][1 + wave][0][0] + j * 1024);
            }
        }
        if (wave == 0 && !fc) { asm volatile("s_waitcnt vmcnt(8)" ::: "memory"); }
        else                  { asm volatile("s_waitcnt vmcnt(4)" ::: "memory"); }
        __hip_atomic_store(&rdy[0][wave], t + 1, __ATOMIC_RELEASE, __HIP_MEMORY_SCOPE_WORKGROUP);
        VMCNT0;
        __hip_atomic_store(&rdy[1][wave], t + 1, __ATOMIC_RELEASE, __HIP_MEMORY_SCOPE_WORKGROUP);

        const int sc = ((kh * 4 + lq) ^ lr);

        // ---- two groups, interleaved ----
        #pragma unroll
        for (int g = 0; g < 2; ++g) {
            // gate: all 8 chunk-stagers done for this group (vectorized LDS check)
            {
                volatile int* vr = &rdy[g][0];
                for (;;) {
                    int m = vr[0];
                    #pragma unroll
                    for (int i = 1; i < 8; ++i) { int u = vr[i]; m = (u < m) ? u : m; }
                    if (m >= t + 1) break;
                }
                __builtin_amdgcn_sched_barrier(0);
            }
            // compute: 9 (or 8) rounds, compiler-pipelined
            f32x4 acc[4] = {};
            if (!fc) {
                const bf16x8 a = *(const bf16x8*)&Als[g][0][lr][sc * 8];
                #pragma unroll
                for (int tc = 0; tc < 4; ++tc)
                    acc[tc] = __builtin_amdgcn_mfma_f32_16x16x32_bf16(w[tc][0], a, acc[tc], 0, 0, 0);
            }
            #pragma unroll
            for (int r = 1; r <= 8; ++r) {
                const bf16x8 a = *(const bf16x8*)&Als[g][r][lr][sc * 8];
                #pragma unroll
                for (int tc = 0; tc < 4; ++tc)
                    acc[tc] = __builtin_amdgcn_mfma_f32_16x16x32_bf16(w[tc][r], a, acc[tc], 0, 0, 0);
            }
            // K-split exchange
            #pragma unroll
            for (int tc = 0; tc < 4; ++tc)
                *(f32x4*)&Xl[kh][cq][tc][lane * 4] = acc[tc];
            __syncthreads();
            // reduce + cell update (wave (cq,kh) owns fragment tc=kh of col-group cq)
            {
                f32x4 z = *(const f32x4*)&Xl[0][cq][kh][lane * 4];
                #pragma unroll
                for (int k2 = 1; k2 < 4; ++k2)
                    z += *(const f32x4*)&Xl[k2][cq][kh][lane * 4];
                const float zi = z[0] + biasq.x;
                const float zf = z[1] + biasq.y;
                const float zg = z[2] + biasq.z;
                const float zo = z[3] + biasq.w;
                const float cn = sigf(zf) * creg[g] + sigf(zi) * tanh_fast(zg);
                creg[g] = cn;
                hTile[g][lr][cq * 16 + lq * 4 + kh] = __float2bfloat16(sigf(zo) * tanh_fast(cn));
            }
            __syncthreads();
            // delegated store+publish: wave g; other waves proceed to next group / next step
            if (wave == g) {
                const int row = lane >> 2, ch = lane & 3;
                *(i32x4*)(hdst + (size_t)(b0 + g * 16 + row) * 1024 + ublk + ch * 8) =
                    *(const i32x4*)&hTile[g][row][ch * 8];
                VMCNT0;
                if (lane == 0) l2_atomic_inc(fbase + (g * 8 + (tile >> 2)) * 16);
            }
        }
    }
}

// ---------- final p-GEMM: out[b][t][f] = hist[t][b] @ W_d + b_d ----------
__global__ __launch_bounds__(256) void pgemm(char* ws, float* __restrict__ out,
                                             const float* __restrict__ bd) {
    const int t = blockIdx.x >> 2;
    const int r0 = (blockIdx.x & 3) * 64;
    const int f0 = blockIdx.y * 64;
    const __hip_bfloat16* A = hist_ptr(ws, t);
    const __hip_bfloat16* Bw = (const __hip_bfloat16*)(ws + OWD);

    __shared__ __hip_bfloat16 Al[2][64 * 64];
    __shared__ __hip_bfloat16 Bl[2][64 * 64];

    const int tid = threadIdx.x;
    const int wave = tid >> 6, lane = tid & 63;
    const int whb = (wave >> 1) * 32, wcf = (wave & 1) * 32;
    const int lr = lane & 15, lq = lane >> 4;
    const int l8 = lane >> 3, cb = lane & 7;
    const int gsw = ((cb ^ l8) << 3);
    const int xk = lr & 7;

    f32x4 acc[2][2] = {};
    const int rA0 = whb + lr, rA1 = whb + lr + 16;
    const int rB0 = wcf + lr, rB1 = wcf + lr + 16;

    auto stage = [&](int buf, int k0) {
        #pragma unroll
        for (int l = 0; l < 2; ++l) {
            const int rt = wave * 16 + l * 8;
            const int row = rt + l8;
            gload_lds16(A + (size_t)(r0 + row) * 1024 + k0 + gsw, &Al[buf][rt * 64]);
            gload_lds16(Bw + (size_t)(f0 + row) * 1024 + k0 + gsw, &Bl[buf][rt * 64]);
        }
    };

    stage(0, 0);
    for (int kk = 0; kk < 16; ++kk) {
        const int buf = kk & 1;
        if (kk + 1 < 16) { stage(buf ^ 1, (kk + 1) << 6); asm volatile("s_waitcnt vmcnt(4)" ::: "memory"); }
        else             { VMCNT0; }
        CFENCE; __builtin_amdgcn_s_barrier(); CFENCE;
        #pragma unroll
        for (int ks = 0; ks < 2; ++ks) {
            const int g0 = ((ks * 4 + lq) ^ xk) << 3;
            bf16x8 a0 = *(const bf16x8*)&Al[buf][rA0 * 64 + g0];
            bf16x8 a1 = *(const bf16x8*)&Al[buf][rA1 * 64 + g0];
            bf16x8 w0 = *(const bf16x8*)&Bl[buf][rB0 * 64 + g0];
            bf16x8 w1 = *(const bf16x8*)&Bl[buf][rB1 * 64 + g0];
            acc[0][0] = __builtin_amdgcn_mfma_f32_16x16x32_bf16(w0, a0, acc[0][0], 0, 0, 0);
            acc[0][1] = __builtin_amdgcn_mfma_f32_16x16x32_bf16(w0, a1, acc[0][1], 0, 0, 0);
            acc[1][0] = __builtin_amdgcn_mfma_f32_16x16x32_bf16(w1, a0, acc[1][0], 0, 0, 0);
            acc[1][1] = __builtin_amdgcn_mfma_f32_16x16x32_bf16(w1, a1, acc[1][1], 0, 0, 0);
        }
        CFENCE; __builtin_amdgcn_s_barrier(); CFENCE;
    }
    #pragma unroll
    for (int cf = 0; cf < 2; ++cf) {
        const int fb = f0 + wcf + cf * 16 + lq * 4;
        const float4 b4 = *(const float4*)(bd + fb);
        #pragma unroll
        for (int rf = 0; rf < 2; ++rf) {
            const int b = r0 + whb + rf * 16 + lr;
            float4 o;
            o.x = acc[cf][rf][0] + b4.x;
            o.y = acc[cf][rf][1] + b4.y;
            o.z = acc[cf][rf][2] + b4.z;
            o.w = acc[cf][rf][3] + b4.w;
            *(float4*)(out + (size_t)b * 16384 + (size_t)t * 128 + fb) = o;
        }
    }
}

// ---------- launcher ----------

extern "C" void kernel_launch(void* const* d_in, const int* in_sizes, int n_in,
                              void* d_out, int out_size, void* d_ws, size_t ws_size,
                              hipStream_t stream) {
    const float* inputs = (const float*)d_in[0];
    const float* W_i    = (const float*)d_in[1];
    const float* W_h    = (const float*)d_in[2];
    const float* b      = (const float*)d_in[3];
    const float* W_d    = (const float*)d_in[4];
    const float* b_d    = (const float*)d_in[5];
    float* out = (float*)d_out;
    char* ws = (char*)d_ws;

    (void)hipMemsetAsync(ws + OHP, 0, HSB, stream);      // h(0) = 0
    (void)hipMemsetAsync(ws + OCNT, 0, 16384, stream);   // flags + slot claim + global counter

    cvt_bf16<<<8192, 256, 0, stream>>>(inputs, (__hip_bfloat16*)(ws + OX), 256 * 256 * 128);
    build_whwi<<<(1152 * 4096) / 256, 256, 0, stream>>>(
        W_h, W_i, (__hip_bfloat16*)(ws + OWH), (__hip_bfloat16*)(ws + OWI));
    build_wd<<<(128 * 1024) / 256, 256, 0, stream>>>(W_d, (__hip_bfloat16*)(ws + OWD));
    build_bias<<<16, 256, 0, stream>>>(b, b_d, W_i, (float*)(ws + OBR), (float*)(ws + OBF));
    build_wf<<<dim3(64, 16), 256, 0, stream>>>(
        (const __hip_bfloat16*)(ws + OWH), (const __hip_bfloat16*)(ws + OWI),
        W_d, (__hip_bfloat16*)(ws + OWF));

    char* wsp = ws;
    void* ka[] = { &wsp };
    (void)hipLaunchCooperativeKernel((void*)persist, dim3(256), dim3(512), ka, 0, stream);

    pgemm<<<dim3(512, 2), 256, 0, stream>>>(ws, out, b_d);
}

// Round 11
// 2094.518 us; speedup vs baseline: 1.3059x; 1.3059x over previous
//
#include <hip/hip_runtime.h>
#include <hip/hip_bf16.h>

// ---- problem sizes ----
#define UNITS 1024
#define FEATS 128
#define NG    4096
#define NSTEP 383            // 256 warmup + 127 forecast
#define HS    262144         // elems per h slice (256*1024)
#define HSB   524288UL       // bytes per h slice

// ---- ws offsets (bytes) ----
#define OX   0UL             // x bf16 [256][256][128]          16,777,216  (hist 1..32)
#define OWH  16777216UL      // WhR [4096][1024] bf16            8,388,608  (hist 33..48)
#define OWI  25165824UL      // WiR [4096][128] bf16             1,048,576  (hist 49..50)
#define OWF  26214400UL      // WfR [4096][1024] bf16            8,388,608  (hist 112..127)
#define OWD  34603008UL      // WdT [128][1024] bf16               262,144
#define OBR  34865152UL      // bias_r [4096] f32                   16,384
#define OBF  34881536UL      // bias_f [4096] f32                   16,384
#define OH0  34897920UL      // hist(0)                            524,288
#define OHP  35422208UL      // hp0, hp1                         1,048,576
#define OHC  36470784UL      // dedicated hist 51..111 (61)     31,981,568
#define OCNT 68452352UL      // flags[8 grp][8 chunk] x 128B = 8192
                             // +8192: agent slotc[8]; +8320: agent global counter

typedef __attribute__((ext_vector_type(8))) short bf16x8;
typedef __attribute__((ext_vector_type(4))) float f32x4;
typedef __attribute__((ext_vector_type(4))) int i32x4;
typedef __attribute__((address_space(3))) char lds_char;
typedef __attribute__((address_space(1))) const char glb_char;

__device__ __forceinline__ void gload_lds16(const void* g, void* l) {
    __builtin_amdgcn_global_load_lds((glb_char*)g, (lds_char*)l, 16, 0, 0);
}
__device__ __forceinline__ int llc_load(const int* p) {
    int v;
    asm volatile("global_load_dword %0, %1, off sc0 sc1\n\ts_waitcnt vmcnt(0)"
                 : "=v"(v) : "v"(p) : "memory");
    return v;
}
__device__ __forceinline__ void l2_atomic_inc(int* p) {
    int one = 1;
    asm volatile("global_atomic_add %0, %1, off" :: "v"(p), "v"(one) : "memory");
}
__device__ __forceinline__ int l2_atomic_poll(int* p) {
    int v; int zero = 0;
    asm volatile("global_atomic_add %0, %1, %2, off sc0\n\ts_waitcnt vmcnt(0)"
                 : "=v"(v) : "v"(p), "v"(zero) : "memory");
    return v;
}

#define CFENCE asm volatile("" ::: "memory")
#define VMCNT0 asm volatile("s_waitcnt vmcnt(0)" ::: "memory")
#define L1INV  asm volatile("buffer_inv" ::: "memory")

__device__ __forceinline__ float sigf(float x) { return 1.0f / (1.0f + __expf(-x)); }
__device__ __forceinline__ float tanh_fast(float x) { return 2.0f / (1.0f + __expf(-2.0f * x)) - 1.0f; }

__device__ __forceinline__ int PK(int k) {
    return (k & ~15) | ((k & 3) << 2) | ((k >> 2) & 3);
}

__device__ __forceinline__ __hip_bfloat16* hist_ptr(char* ws, int s) {
    size_t off;
    if (s == 0)        off = OH0;
    else if (s <= 32)  off = OX  + (size_t)(s - 1) * HSB;
    else if (s <= 48)  off = OWH + (size_t)(s - 33) * HSB;
    else if (s <= 50)  off = OWI + (size_t)(s - 49) * HSB;
    else if (s <= 111) off = OHC + (size_t)(s - 51) * HSB;
    else               off = OWF + (size_t)(s - 112) * HSB;
    return (__hip_bfloat16*)(ws + off);
}

__device__ __forceinline__ void llc_sync(int* c, int target) {
    CFENCE;
    __syncthreads();
    if (threadIdx.x == 0) {
        atomicAdd(c, 1);
        while (llc_load(c) < target) __builtin_amdgcn_s_sleep(8);
    }
    __syncthreads();
    CFENCE;
}

// ---------- precompute kernels ----------

__global__ void cvt_bf16(const float* __restrict__ in, __hip_bfloat16* __restrict__ out, int n) {
    int i = (blockIdx.x * blockDim.x + threadIdx.x) * 4;
    if (i >= n) return;
    float4 v = *(const float4*)(in + i);
    union { ushort4 u4; __hip_bfloat16 h[4]; } pk;
    pk.h[0] = __float2bfloat16(v.x);
    pk.h[1] = __float2bfloat16(v.y);
    pk.h[2] = __float2bfloat16(v.z);
    pk.h[3] = __float2bfloat16(v.w);
    *(ushort4*)(out + i) = pk.u4;
}

__global__ void build_whwi(const float* __restrict__ Wh, const float* __restrict__ Wi,
                           __hip_bfloat16* __restrict__ WhR, __hip_bfloat16* __restrict__ WiR) {
    int idx = blockIdx.x * 256 + threadIdx.x;
    int k = idx >> 12, col = idx & 4095;
    int j = ((col & 1023) << 2) | (col >> 10);
    if (k < 1024) WhR[(size_t)j * 1024 + k] = __float2bfloat16(Wh[(size_t)PK(k) * 4096 + col]);
    else          WiR[(size_t)j * 128 + (k - 1024)] = __float2bfloat16(Wi[(size_t)(k - 1024) * 4096 + col]);
}

__global__ void build_wd(const float* __restrict__ Wd, __hip_bfloat16* __restrict__ WdT) {
    int idx = blockIdx.x * 256 + threadIdx.x;
    int f = idx >> 10, k = idx & 1023;
    WdT[(size_t)f * 1024 + k] = __float2bfloat16(Wd[(size_t)PK(k) * 128 + f]);
}

__global__ void build_bias(const float* __restrict__ b, const float* __restrict__ bd,
                           const float* __restrict__ Wi, float* __restrict__ br, float* __restrict__ bf) {
    int j = blockIdx.x * 256 + threadIdx.x;
    int col = ((j & 3) << 10) | (j >> 2);
    float base = b[col];
    br[j] = base;
    float v = base;
    for (int q = 0; q < 128; ++q) v += bd[q] * Wi[(size_t)q * 4096 + col];
    bf[j] = v;
}

__global__ __launch_bounds__(256) void build_wf(const __hip_bfloat16* __restrict__ WhR,
                                                const __hip_bfloat16* __restrict__ WiR,
                                                const float* __restrict__ Wd,
                                                __hip_bfloat16* __restrict__ WfR) {
    const int j0 = blockIdx.x * 64, k0 = blockIdx.y * 64;
    const int tid = threadIdx.x, wave = tid >> 6, lane = tid & 63;
    const int wj = (wave >> 1) * 32, wk = (wave & 1) * 32;
    const int lr = lane & 15, lq = lane >> 4;
    const int TL = ((lr & 3) << 2) | (lr >> 2);
    f32x4 acc[2][2] = {};
    #pragma unroll
    for (int kc = 0; kc < 4; ++kc) {
        bf16x8 dfr[2], ifr[2];
        #pragma unroll
        for (int q2 = 0; q2 < 2; ++q2) {
            const float* p = Wd + (size_t)(k0 + wk + q2 * 16 + TL) * 128 + kc * 32 + lq * 8;
            __hip_bfloat16* dp = (__hip_bfloat16*)&dfr[q2];
            #pragma unroll
            for (int e = 0; e < 8; ++e) dp[e] = __float2bfloat16(p[e]);
            ifr[q2] = *(const bf16x8*)(WiR + (size_t)(j0 + wj + q2 * 16 + lr) * 128 + kc * 32 + lq * 8);
        }
        acc[0][0] = __builtin_amdgcn_mfma_f32_16x16x32_bf16(dfr[0], ifr[0], acc[0][0], 0, 0, 0);
        acc[0][1] = __builtin_amdgcn_mfma_f32_16x16x32_bf16(dfr[0], ifr[1], acc[0][1], 0, 0, 0);
        acc[1][0] = __builtin_amdgcn_mfma_f32_16x16x32_bf16(dfr[1], ifr[0], acc[1][0], 0, 0, 0);
        acc[1][1] = __builtin_amdgcn_mfma_f32_16x16x32_bf16(dfr[1], ifr[1], acc[1][1], 0, 0, 0);
    }
    #pragma unroll
    for (int cf = 0; cf < 2; ++cf)
        #pragma unroll
        for (int rf = 0; rf < 2; ++rf) {
            const int k = k0 + wk + cf * 16 + lq * 4;
            const int j = j0 + wj + rf * 16 + lr;
            const __hip_bfloat16* whp = WhR + (size_t)j * 1024 + k;
            __hip_bfloat16* wfp = WfR + (size_t)j * 1024 + k;
            #pragma unroll
            for (int e = 0; e < 4; ++e)
                wfp[e] = __float2bfloat16(acc[cf][rf][e] + __bfloat162float(whp[e]));
        }
}

// ---------- persistent LSTM kernel: full-K per wave, zero-exchange epilogue ----------
// Wave w owns gate-cols [n0+16w, n0+16w+16) over the FULL K. MFMA D layout puts the
// 4 gates of unit (tile*32 + w*4 + lq), batch lr/lr+16 directly in lane (lq,lr)'s acc.
__global__ __launch_bounds__(512, 2) void persist(char* ws) {
    const __hip_bfloat16* xb  = (const __hip_bfloat16*)(ws + OX);
    const __hip_bfloat16* whg = (const __hip_bfloat16*)(ws + OWH);
    const __hip_bfloat16* wig = (const __hip_bfloat16*)(ws + OWI);
    const __hip_bfloat16* wfg = (const __hip_bfloat16*)(ws + OWF);
    const float* brg = (const float*)(ws + OBR);
    const float* bfg = (const float*)(ws + OBF);
    __hip_bfloat16* hp0 = (__hip_bfloat16*)(ws + OHP);
    __hip_bfloat16* hp1 = hp0 + HS;

    __shared__ __hip_bfloat16 Als[9][32][128];   // 73,728 B: chunk 0 = x, 1+c = h units [128c..)
    __shared__ __hip_bfloat16 hTile[2][32][32];  //  4,096 B: double-buffered h bounce
    __shared__ int claimv[2];
    __shared__ int rdy[12];                      // 0..7 h chunks, 8 = x (monotone step tags)

    const int tid = threadIdx.x;

    if (tid < 12) rdy[tid] = 0;
    if (tid == 0) {
        unsigned xcd;
        asm volatile("s_getreg_b32 %0, hwreg(HW_REG_XCC_ID, 0, 32)" : "=s"(xcd));
        int* slotc = (int*)(ws + OCNT + 8192);
        int slot = atomicAdd(slotc + (xcd & 7), 1);
        claimv[0] = (int)(xcd & 7);
        claimv[1] = slot & 31;
    }
    __syncthreads();
    const int grp  = claimv[0];         // batch group == physical XCD
    const int tile = claimv[1];         // gate-col tile within group
    const int n0 = tile * 128;
    const int b0 = grp * 32;
    const int ublk = tile * 32;
    int* fbase = (int*)(ws + OCNT + (size_t)grp * 1024);   // flags[grp][c] at +c*128B
    int* glc   = (int*)(ws + OCNT + 8320);

    const int wave = tid >> 6, lane = tid & 63;
    const int lr = lane & 15, lq = lane >> 4;

    // weights -> registers: wv[0..3] = Wi ksteps (x), wv[4+4c+s] = Wh chunk c kstep s.
    const size_t wrow = (size_t)(n0 + wave * 16 + lr);
    bf16x8 wv[36];
    #pragma unroll
    for (int s = 0; s < 4; ++s)
        wv[s] = *(const bf16x8*)(wig + wrow * 128 + s * 32 + lq * 8);
    #pragma unroll
    for (int c = 0; c < 8; ++c)
        #pragma unroll
        for (int s = 0; s < 4; ++s)
            wv[4 + 4 * c + s] = *(const bf16x8*)(whg + wrow * 1024 + c * 128 + s * 32 + lq * 8);
    float4 biasq = *(const float4*)(brg + n0 + wave * 16 + lq * 4);
    float creg[2] = {0.f, 0.f};   // cell: unit tile*32 + wave*4 + lq, batches lr / lr+16

    // stager geometry: wave w stages h chunk w (32 rows x 128 kvals), 8 x 1KB loads
    const int sr = lane >> 4;           // row-within-4
    const int scol = lane & 15;         // 16B chunk in row
    // PK-permuted local unit position for h store
    const int upos = ((wave >> 2) << 4) | (lq << 2) | (wave & 3);

    for (int t = 0; t < NSTEP; ++t) {
        const bool fc = (t >= 256);
        const __hip_bfloat16* hsrc = fc ? hist_ptr(ws, t - 256) : ((t & 1) ? hp1 : hp0);
        __hip_bfloat16* hdst = (t >= 255) ? hist_ptr(ws, t - 255) : ((t & 1) ? hp0 : hp1);

        if (t == 256) {   // folded forecast weights, then one global barrier
            #pragma unroll
            for (int c = 0; c < 8; ++c)
                #pragma unroll
                for (int s = 0; s < 4; ++s)
                    wv[4 + 4 * c + s] = *(const bf16x8*)(wfg + wrow * 1024 + c * 128 + s * 32 + lq * 8);
            biasq = *(const float4*)(bfg + n0 + wave * 16 + lq * 4);
            VMCNT0;
            llc_sync(glc, 256);
        }

        // ---- poll own chunk's producers, then stage own chunk ----
        if (t > 0 && lane == 0) {
            int* fl = fbase + wave * 32;
            while (l2_atomic_poll(fl) < 4 * t) { }
        }
        L1INV;
        {
            const __hip_bfloat16* srcb = hsrc + (size_t)b0 * 1024 + wave * 128;
            char* dstc = (char*)&Als[1 + wave][0][0];
            #pragma unroll
            for (int j = 0; j < 8; ++j) {
                const int row = j * 4 + sr;
                const int ce = (scol ^ (row & 15)) << 3;
                gload_lds16(srcb + (size_t)row * 1024 + ce, dstc + j * 1024);
            }
        }
        if (wave == 0) {
            if (!fc) {
                #pragma unroll
                for (int j = 0; j < 8; ++j) {
                    const int row = j * 4 + sr;
                    const int ce = (scol ^ (row & 15)) << 3;
                    gload_lds16(xb + (size_t)(b0 + row) * 32768 + (size_t)t * 128 + ce,
                                (char*)&Als[0][0][0] + j * 1024);
                }
                asm volatile("s_waitcnt vmcnt(8)" ::: "memory");
                __hip_atomic_store(&rdy[0], t + 1, __ATOMIC_RELEASE, __HIP_MEMORY_SCOPE_WORKGROUP);
                VMCNT0;
                __hip_atomic_store(&rdy[8], t + 1, __ATOMIC_RELEASE, __HIP_MEMORY_SCOPE_WORKGROUP);
            } else {
                VMCNT0;
                __hip_atomic_store(&rdy[0], t + 1, __ATOMIC_RELEASE, __HIP_MEMORY_SCOPE_WORKGROUP);
            }
        } else {
            VMCNT0;
            __hip_atomic_store(&rdy[wave], t + 1, __ATOMIC_RELEASE, __HIP_MEMORY_SCOPE_WORKGROUP);
        }

        // ---- compute: full K, per-chunk gates; 4 independent MFMA chains ----
        f32x4 acc[2][2] = {};
        auto gate = [&](int idx) {
            while (__hip_atomic_load(&rdy[idx], __ATOMIC_ACQUIRE, __HIP_MEMORY_SCOPE_WORKGROUP) < t + 1) {}
            __builtin_amdgcn_sched_barrier(0);
        };
        auto chunk = [&](int r, int wbase) {
            #pragma unroll
            for (int s = 0; s < 4; ++s) {
                const int sc = ((s * 4 + lq) ^ lr) << 3;
                const bf16x8 a0 = *(const bf16x8*)&Als[r][lr][sc];
                const bf16x8 a1 = *(const bf16x8*)&Als[r][lr + 16][sc];
                acc[0][s & 1] = __builtin_amdgcn_mfma_f32_16x16x32_bf16(wv[wbase + s], a0, acc[0][s & 1], 0, 0, 0);
                acc[1][s & 1] = __builtin_amdgcn_mfma_f32_16x16x32_bf16(wv[wbase + s], a1, acc[1][s & 1], 0, 0, 0);
            }
        };
        #pragma unroll
        for (int c = 0; c < 8; ++c) { gate(c); chunk(1 + c, 4 + 4 * c); }
        if (!fc) { gate(8); chunk(0, 0); }

        // ---- zero-exchange cell update: lane owns its unit's 4 gates directly ----
        {
            const f32x4 z0 = acc[0][0] + acc[0][1];
            const f32x4 z1 = acc[1][0] + acc[1][1];
            {
                const float zi = z0[0] + biasq.x, zf = z0[1] + biasq.y;
                const float zg = z0[2] + biasq.z, zo = z0[3] + biasq.w;
                const float cn = sigf(zf) * creg[0] + sigf(zi) * tanh_fast(zg);
                creg[0] = cn;
                hTile[t & 1][lr][upos] = __float2bfloat16(sigf(zo) * tanh_fast(cn));
            }
            {
                const float zi = z1[0] + biasq.x, zf = z1[1] + biasq.y;
                const float zg = z1[2] + biasq.z, zo = z1[3] + biasq.w;
                const float cn = sigf(zf) * creg[1] + sigf(zi) * tanh_fast(zg);
                creg[1] = cn;
                hTile[t & 1][16 + lr][upos] = __float2bfloat16(sigf(zo) * tanh_fast(cn));
            }
        }
        __syncthreads();   // hTile complete; also orders Als reads before next restage

        // ---- delegated store + publish (wave 7); others roll into next step ----
        if (wave == 7) {
            #pragma unroll
            for (int i = 0; i < 2; ++i) {
                const int q = lane + i * 64;            // 16B chunk 0..127
                const int row = q >> 2, ch = q & 3;
                *(i32x4*)(hdst + (size_t)(b0 + row) * 1024 + ublk + ch * 8) =
                    *(const i32x4*)&hTile[t & 1][row][ch * 8];
            }
            VMCNT0;
            if (lane == 0) l2_atomic_inc(fbase + (tile >> 2) * 32);
        }
    }
}

// ---------- final p-GEMM: out[b][t][f] = hist[t][b] @ W_d + b_d ----------
__global__ __launch_bounds__(256) void pgemm(char* ws, float* __restrict__ out,
                                             const float* __restrict__ bd) {
    const int t = blockIdx.x >> 2;
    const int r0 = (blockIdx.x & 3) * 64;
    const int f0 = blockIdx.y * 64;
    const __hip_bfloat16* A = hist_ptr(ws, t);
    const __hip_bfloat16* Bw = (const __hip_bfloat16*)(ws + OWD);

    __shared__ __hip_bfloat16 Al[2][64 * 64];
    __shared__ __hip_bfloat16 Bl[2][64 * 64];

    const int tid = threadIdx.x;
    const int wave = tid >> 6, lane = tid & 63;
    const int whb = (wave >> 1) * 32, wcf = (wave & 1) * 32;
    const int lr = lane & 15, lq = lane >> 4;
    const int l8 = lane >> 3, cb = lane & 7;
    const int gsw = ((cb ^ l8) << 3);
    const int xk = lr & 7;

    f32x4 acc[2][2] = {};
    const int rA0 = whb + lr, rA1 = whb + lr + 16;
    const int rB0 = wcf + lr, rB1 = wcf + lr + 16;

    auto stage = [&](int buf, int k0) {
        #pragma unroll
        for (int l = 0; l < 2; ++l) {
            const int rt = wave * 16 + l * 8;
            const int row = rt + l8;
            gload_lds16(A + (size_t)(r0 + row) * 1024 + k0 + gsw, &Al[buf][rt * 64]);
            gload_lds16(Bw + (size_t)(f0 + row) * 1024 + k0 + gsw, &Bl[buf][rt * 64]);
        }
    };

    stage(0, 0);
    for (int kk = 0; kk < 16; ++kk) {
        const int buf = kk & 1;
        if (kk + 1 < 16) { stage(buf ^ 1, (kk + 1) << 6); asm volatile("s_waitcnt vmcnt(4)" ::: "memory"); }
        else             { VMCNT0; }
        CFENCE; __builtin_amdgcn_s_barrier(); CFENCE;
        #pragma unroll
        for (int ks = 0; ks < 2; ++ks) {
            const int g0 = ((ks * 4 + lq) ^ xk) << 3;
            bf16x8 a0 = *(const bf16x8*)&Al[buf][rA0 * 64 + g0];
            bf16x8 a1 = *(const bf16x8*)&Al[buf][rA1 * 64 + g0];
            bf16x8 w0 = *(const bf16x8*)&Bl[buf][rB0 * 64 + g0];
            bf16x8 w1 = *(const bf16x8*)&Bl[buf][rB1 * 64 + g0];
            acc[0][0] = __builtin_amdgcn_mfma_f32_16x16x32_bf16(w0, a0, acc[0][0], 0, 0, 0);
            acc[0][1] = __builtin_amdgcn_mfma_f32_16x16x32_bf16(w0, a1, acc[0][1], 0, 0, 0);
            acc[1][0] = __builtin_amdgcn_mfma_f32_16x16x32_bf16(w1, a0, acc[1][0], 0, 0, 0);
            acc[1][1] = __builtin_amdgcn_mfma_f32_16x16x32_bf16(w1, a1, acc[1][1], 0, 0, 0);
        }
        CFENCE; __builtin_amdgcn_s_barrier(); CFENCE;
    }
    #pragma unroll
    for (int cf = 0; cf < 2; ++cf) {
        const int fb = f0 + wcf + cf * 16 + lq * 4;
        const float4 b4 = *(const float4*)(bd + fb);
        #pragma unroll
        for (int rf = 0; rf < 2; ++rf) {
            const int b = r0 + whb + rf * 16 + lr;
            float4 o;
            o.x = acc[cf][rf][0] + b4.x;
            o.y = acc[cf][rf][1] + b4.y;
            o.z = acc[cf][rf][2] + b4.z;
            o.w = acc[cf][rf][3] + b4.w;
            *(float4*)(out + (size_t)b * 16384 + (size_t)t * 128 + fb) = o;
        }
    }
}

// ---------- launcher ----------

extern "C" void kernel_launch(void* const* d_in, const int* in_sizes, int n_in,
                              void* d_out, int out_size, void* d_ws, size_t ws_size,
                              hipStream_t stream) {
    const float* inputs = (const float*)d_in[0];
    const float* W_i    = (const float*)d_in[1];
    const float* W_h    = (const float*)d_in[2];
    const float* b      = (const float*)d_in[3];
    const float* W_d    = (const float*)d_in[4];
    const float* b_d    = (const float*)d_in[5];
    float* out = (float*)d_out;
    char* ws = (char*)d_ws;

    (void)hipMemsetAsync(ws + OHP, 0, HSB, stream);      // h(0) = 0
    (void)hipMemsetAsync(ws + OCNT, 0, 16384, stream);   // flags + slot claim + global counter

    cvt_bf16<<<8192, 256, 0, stream>>>(inputs, (__hip_bfloat16*)(ws + OX), 256 * 256 * 128);
    build_whwi<<<(1152 * 4096) / 256, 256, 0, stream>>>(
        W_h, W_i, (__hip_bfloat16*)(ws + OWH), (__hip_bfloat16*)(ws + OWI));
    build_wd<<<(128 * 1024) / 256, 256, 0, stream>>>(W_d, (__hip_bfloat16*)(ws + OWD));
    build_bias<<<16, 256, 0, stream>>>(b, b_d, W_i, (float*)(ws + OBR), (float*)(ws + OBF));
    build_wf<<<dim3(64, 16), 256, 0, stream>>>(
        (const __hip_bfloat16*)(ws + OWH), (const __hip_bfloat16*)(ws + OWI),
        W_d, (__hip_bfloat16*)(ws + OWF));

    char* wsp = ws;
    void* ka[] = { &wsp };
    (void)hipLaunchCooperativeKernel((void*)persist, dim3(256), dim3(512), ka, 0, stream);

    pgemm<<<dim3(512, 2), 256, 0, stream>>>(ws, out, b_d);
}

// Round 12
// 1738.860 us; speedup vs baseline: 1.5731x; 1.2045x over previous
//
#include <hip/hip_runtime.h>
#include <hip/hip_bf16.h>

// ---- problem sizes ----
#define UNITS 1024
#define FEATS 128
#define NG    4096
#define NSTEP 383            // 256 warmup + 127 forecast
#define HS    262144         // elems per h slice (256*1024)
#define HSB   524288UL       // bytes per h slice

// ---- ws offsets (bytes) ----
#define OX   0UL             // x bf16 [256][256][128]          16,777,216  (hist 1..32)
#define OWH  16777216UL      // WhR [4096][1024] bf16            8,388,608  (hist 33..48)
#define OWI  25165824UL      // WiR [4096][128] bf16             1,048,576  (hist 49..50)
#define OWF  26214400UL      // WfR [4096][1024] bf16            8,388,608  (hist 112..127)
#define OWD  34603008UL      // WdT [128][1024] bf16               262,144
#define OBR  34865152UL      // bias_r [4096] f32                   16,384
#define OBF  34881536UL      // bias_f [4096] f32                   16,384
#define OH0  34897920UL      // hist(0)                            524,288
#define OHP  35422208UL      // hp0, hp1                         1,048,576
#define OHC  36470784UL      // dedicated hist 51..111 (61)     31,981,568
#define OCNT 68452352UL      // private flags[8 grp][32 cons][8 chunk] x 128B = 262,144
                             // +262144: agent slotc[8]; +262272: agent global counter

typedef __attribute__((ext_vector_type(8))) short bf16x8;
typedef __attribute__((ext_vector_type(4))) float f32x4;
typedef __attribute__((ext_vector_type(4))) int i32x4;
typedef __attribute__((address_space(3))) char lds_char;
typedef __attribute__((address_space(1))) const char glb_char;

__device__ __forceinline__ void gload_lds16(const void* g, void* l) {
    __builtin_amdgcn_global_load_lds((glb_char*)g, (lds_char*)l, 16, 0, 0);
}
// sc0 variant: request L1 bypass on the read path (L1INV retained as correctness belt)
__device__ __forceinline__ void gload_lds16_sc0(const void* g, void* l) {
    __builtin_amdgcn_global_load_lds((glb_char*)g, (lds_char*)l, 16, 0, 1);
}
__device__ __forceinline__ int llc_load(const int* p) {
    int v;
    asm volatile("global_load_dword %0, %1, off sc0 sc1\n\ts_waitcnt vmcnt(0)"
                 : "=v"(v) : "v"(p) : "memory");
    return v;
}
__device__ __forceinline__ void l2_atomic_inc(int* p) {
    int one = 1;
    asm volatile("global_atomic_add %0, %1, off" :: "v"(p), "v"(one) : "memory");
}
__device__ __forceinline__ int l2_atomic_poll(int* p) {
    int v; int zero = 0;
    asm volatile("global_atomic_add %0, %1, %2, off sc0\n\ts_waitcnt vmcnt(0)"
                 : "=v"(v) : "v"(p), "v"(zero) : "memory");
    return v;
}

#define CFENCE asm volatile("" ::: "memory")
#define VMCNT0 asm volatile("s_waitcnt vmcnt(0)" ::: "memory")
#define L1INV  asm volatile("buffer_inv" ::: "memory")

__device__ __forceinline__ float sigf(float x) { return 1.0f / (1.0f + __expf(-x)); }
__device__ __forceinline__ float tanh_fast(float x) { return 2.0f / (1.0f + __expf(-2.0f * x)) - 1.0f; }

__device__ __forceinline__ int PK(int k) {
    return (k & ~15) | ((k & 3) << 2) | ((k >> 2) & 3);
}

__device__ __forceinline__ __hip_bfloat16* hist_ptr(char* ws, int s) {
    size_t off;
    if (s == 0)        off = OH0;
    else if (s <= 32)  off = OX  + (size_t)(s - 1) * HSB;
    else if (s <= 48)  off = OWH + (size_t)(s - 33) * HSB;
    else if (s <= 50)  off = OWI + (size_t)(s - 49) * HSB;
    else if (s <= 111) off = OHC + (size_t)(s - 51) * HSB;
    else               off = OWF + (size_t)(s - 112) * HSB;
    return (__hip_bfloat16*)(ws + off);
}

__device__ __forceinline__ void llc_sync(int* c, int target) {
    CFENCE;
    __syncthreads();
    if (threadIdx.x == 0) {
        atomicAdd(c, 1);
        while (llc_load(c) < target) __builtin_amdgcn_s_sleep(8);
    }
    __syncthreads();
    CFENCE;
}

// ---------- precompute kernels ----------

__global__ void cvt_bf16(const float* __restrict__ in, __hip_bfloat16* __restrict__ out, int n) {
    int i = (blockIdx.x * blockDim.x + threadIdx.x) * 4;
    if (i >= n) return;
    float4 v = *(const float4*)(in + i);
    union { ushort4 u4; __hip_bfloat16 h[4]; } pk;
    pk.h[0] = __float2bfloat16(v.x);
    pk.h[1] = __float2bfloat16(v.y);
    pk.h[2] = __float2bfloat16(v.z);
    pk.h[3] = __float2bfloat16(v.w);
    *(ushort4*)(out + i) = pk.u4;
}

__global__ void build_whwi(const float* __restrict__ Wh, const float* __restrict__ Wi,
                           __hip_bfloat16* __restrict__ WhR, __hip_bfloat16* __restrict__ WiR) {
    int idx = blockIdx.x * 256 + threadIdx.x;
    int k = idx >> 12, col = idx & 4095;
    int j = ((col & 1023) << 2) | (col >> 10);
    if (k < 1024) WhR[(size_t)j * 1024 + k] = __float2bfloat16(Wh[(size_t)PK(k) * 4096 + col]);
    else          WiR[(size_t)j * 128 + (k - 1024)] = __float2bfloat16(Wi[(size_t)(k - 1024) * 4096 + col]);
}

__global__ void build_wd(const float* __restrict__ Wd, __hip_bfloat16* __restrict__ WdT) {
    int idx = blockIdx.x * 256 + threadIdx.x;
    int f = idx >> 10, k = idx & 1023;
    WdT[(size_t)f * 1024 + k] = __float2bfloat16(Wd[(size_t)PK(k) * 128 + f]);
}

__global__ void build_bias(const float* __restrict__ b, const float* __restrict__ bd,
                           const float* __restrict__ Wi, float* __restrict__ br, float* __restrict__ bf) {
    int j = blockIdx.x * 256 + threadIdx.x;
    int col = ((j & 3) << 10) | (j >> 2);
    float base = b[col];
    br[j] = base;
    float v = base;
    for (int q = 0; q < 128; ++q) v += bd[q] * Wi[(size_t)q * 4096 + col];
    bf[j] = v;
}

__global__ __launch_bounds__(256) void build_wf(const __hip_bfloat16* __restrict__ WhR,
                                                const __hip_bfloat16* __restrict__ WiR,
                                                const float* __restrict__ Wd,
                                                __hip_bfloat16* __restrict__ WfR) {
    const int j0 = blockIdx.x * 64, k0 = blockIdx.y * 64;
    const int tid = threadIdx.x, wave = tid >> 6, lane = tid & 63;
    const int wj = (wave >> 1) * 32, wk = (wave & 1) * 32;
    const int lr = lane & 15, lq = lane >> 4;
    const int TL = ((lr & 3) << 2) | (lr >> 2);
    f32x4 acc[2][2] = {};
    #pragma unroll
    for (int kc = 0; kc < 4; ++kc) {
        bf16x8 dfr[2], ifr[2];
        #pragma unroll
        for (int q2 = 0; q2 < 2; ++q2) {
            const float* p = Wd + (size_t)(k0 + wk + q2 * 16 + TL) * 128 + kc * 32 + lq * 8;
            __hip_bfloat16* dp = (__hip_bfloat16*)&dfr[q2];
            #pragma unroll
            for (int e = 0; e < 8; ++e) dp[e] = __float2bfloat16(p[e]);
            ifr[q2] = *(const bf16x8*)(WiR + (size_t)(j0 + wj + q2 * 16 + lr) * 128 + kc * 32 + lq * 8);
        }
        acc[0][0] = __builtin_amdgcn_mfma_f32_16x16x32_bf16(dfr[0], ifr[0], acc[0][0], 0, 0, 0);
        acc[0][1] = __builtin_amdgcn_mfma_f32_16x16x32_bf16(dfr[0], ifr[1], acc[0][1], 0, 0, 0);
        acc[1][0] = __builtin_amdgcn_mfma_f32_16x16x32_bf16(dfr[1], ifr[0], acc[1][0], 0, 0, 0);
        acc[1][1] = __builtin_amdgcn_mfma_f32_16x16x32_bf16(dfr[1], ifr[1], acc[1][1], 0, 0, 0);
    }
    #pragma unroll
    for (int cf = 0; cf < 2; ++cf)
        #pragma unroll
        for (int rf = 0; rf < 2; ++rf) {
            const int k = k0 + wk + cf * 16 + lq * 4;
            const int j = j0 + wj + rf * 16 + lr;
            const __hip_bfloat16* whp = WhR + (size_t)j * 1024 + k;
            __hip_bfloat16* wfp = WfR + (size_t)j * 1024 + k;
            #pragma unroll
            for (int e = 0; e < 4; ++e)
                wfp[e] = __float2bfloat16(acc[cf][rf][e] + __bfloat162float(whp[e]));
        }
}

// ---------- persistent LSTM kernel (R9 base + private flags + distributed epilogue) ----------
__global__ __launch_bounds__(512, 2) void persist(char* ws) {
    const __hip_bfloat16* xb  = (const __hip_bfloat16*)(ws + OX);
    const __hip_bfloat16* whg = (const __hip_bfloat16*)(ws + OWH);
    const __hip_bfloat16* wig = (const __hip_bfloat16*)(ws + OWI);
    const __hip_bfloat16* wfg = (const __hip_bfloat16*)(ws + OWF);
    const float* brg = (const float*)(ws + OBR);
    const float* bfg = (const float*)(ws + OBF);
    __hip_bfloat16* hp0 = (__hip_bfloat16*)(ws + OHP);
    __hip_bfloat16* hp1 = hp0 + HS;

    __shared__ __hip_bfloat16 Als[9][32][128];   // 73,728 B: Als[0]=x, Als[1+c]=h chunk c
    __shared__ float Xl[4][2][4][2][256];        // 65,536 B: K-split exchange
    __shared__ __hip_bfloat16 hTile[32][32];     //  2,048 B
    __shared__ int claimv[2];
    __shared__ int rdy[12];                      // 0..7: h chunks, 8: x (monotone tags)

    const int tid = threadIdx.x;

    if (tid < 12) rdy[tid] = 0;
    if (tid == 0) {
        unsigned xcd;
        asm volatile("s_getreg_b32 %0, hwreg(HW_REG_XCC_ID, 0, 32)" : "=s"(xcd));
        int* slotc = (int*)(ws + OCNT + 262144);
        int slot = atomicAdd(slotc + (xcd & 7), 1);
        claimv[0] = (int)(xcd & 7);
        claimv[1] = slot & 31;
    }
    __syncthreads();
    const int grp  = claimv[0];
    const int tile = claimv[1];
    const int n0 = tile * 128;
    const int b0 = grp * 32;
    const int ublk = tile * 32;
    int* flg = (int*)(ws + OCNT);
    int* glc = (int*)(ws + OCNT + 262144 + 128);
    // private flag line for (consumer block `cons`, chunk): 128B apart
    auto flag_at = [&](int cons, int chunk) {
        return flg + ((size_t)(grp * 32 + cons) * 8 + chunk) * 32;
    };

    const int wave = tid >> 6, lane = tid & 63;
    const int cq = wave & 1, kh = wave >> 1;     // col 64-half, K-quarter
    const int lr = lane & 15, lq = lane >> 4;

    // weights -> registers: w[tc][0]=Wi chunk; w[tc][1+c]=Wh chunk c (this wave's K-quarter)
    bf16x8 w[4][9];
    #pragma unroll
    for (int tc = 0; tc < 4; ++tc) {
        const size_t row = (size_t)(n0 + cq * 64 + tc * 16 + lr);
        w[tc][0] = *(const bf16x8*)(wig + row * 128 + kh * 32 + lq * 8);
        #pragma unroll
        for (int c = 0; c < 8; ++c)
            w[tc][1 + c] = *(const bf16x8*)(whg + row * 1024 + c * 128 + kh * 32 + lq * 8);
    }
    // bias quad for the fragment this wave OWNS in the epilogue (tc == kh)
    float4 biasq = *(const float4*)(brg + n0 + cq * 64 + kh * 16 + lq * 4);
    float creg[2] = {0.f, 0.f};   // cell: unit cq*16+kh*4+lq, batches lr / lr+16

    // stager geometry
    const int sr = lane >> 4;            // 0..3
    const int scol = lane & 15;          // 16B chunk within row

    // prologue: x(0) prefetch by wave 0
    if (wave == 0) {
        #pragma unroll
        for (int j = 0; j < 8; ++j) {
            const int row = j * 4 + sr;
            const int ce = (scol ^ (row & 15)) << 3;
            gload_lds16(xb + (size_t)(b0 + row) * 32768 + ce,
                        (char*)&Als[0][0][0] + j * 1024);
        }
    }

    for (int t = 0; t < NSTEP; ++t) {
        const bool fc = (t >= 256);
        const __hip_bfloat16* hsrc = fc ? hist_ptr(ws, t - 256) : ((t & 1) ? hp1 : hp0);
        __hip_bfloat16* hdst = (t >= 255) ? hist_ptr(ws, t - 255) : ((t & 1) ? hp0 : hp1);

        if (t == 256) {   // folded forecast weights, then one global barrier
            #pragma unroll
            for (int tc = 0; tc < 4; ++tc) {
                const size_t row = (size_t)(n0 + cq * 64 + tc * 16 + lr);
                #pragma unroll
                for (int c = 0; c < 8; ++c)
                    w[tc][1 + c] = *(const bf16x8*)(wfg + row * 1024 + c * 128 + kh * 32 + lq * 8);
            }
            biasq = *(const float4*)(bfg + n0 + cq * 64 + kh * 16 + lq * 4);
            VMCNT0;
            llc_sync(glc, 256);
        }

        // ---- gate on PRIVATE flag (8 incs per chunk per step), then stage own chunk ----
        if (t > 0 && lane == 0) {
            int* fl = flag_at(tile, wave);
            while (l2_atomic_poll(fl) < 8 * t) { }
        }
        L1INV;
        {
            const __hip_bfloat16* srcb = hsrc + (size_t)b0 * 1024 + wave * 128;
            char* dstc = (char*)&Als[1 + wave][0][0];
            #pragma unroll
            for (int j = 0; j < 8; ++j) {
                const int row = j * 4 + sr;
                const int ce = (scol ^ (row & 15)) << 3;
                gload_lds16_sc0(srcb + (size_t)row * 1024 + ce, dstc + j * 1024);
            }
        }
        VMCNT0;   // drains h chunk (and wave 0's outstanding x prefetch)
        __hip_atomic_store(&rdy[wave], t + 1, __ATOMIC_RELEASE, __HIP_MEMORY_SCOPE_WORKGROUP);
        if (wave == 0 && !fc)
            __hip_atomic_store(&rdy[8], t + 1, __ATOMIC_RELEASE, __HIP_MEMORY_SCOPE_WORKGROUP);

        // ---- compute: 9 (8 in fc) rounds gated per chunk ----
        f32x4 acc[4][2] = {};
        auto gate = [&](int idx) {
            while (__hip_atomic_load(&rdy[idx], __ATOMIC_ACQUIRE, __HIP_MEMORY_SCOPE_WORKGROUP) < t + 1) {}
            __builtin_amdgcn_sched_barrier(0);
        };
        const int sc = ((kh * 4 + lq) ^ lr);
        auto mfr = [&](int r) {
            const bf16x8 a0 = *(const bf16x8*)&Als[r][lr][sc * 8];
            const bf16x8 a1 = *(const bf16x8*)&Als[r][lr + 16][sc * 8];
            #pragma unroll
            for (int tc = 0; tc < 4; ++tc) {
                acc[tc][0] = __builtin_amdgcn_mfma_f32_16x16x32_bf16(w[tc][r], a0, acc[tc][0], 0, 0, 0);
                acc[tc][1] = __builtin_amdgcn_mfma_f32_16x16x32_bf16(w[tc][r], a1, acc[tc][1], 0, 0, 0);
            }
        };
        if (!fc) { gate(8); mfr(0); }
        #pragma unroll
        for (int r = 1; r <= 8; ++r) { gate(r - 1); mfr(r); }

        // ---- distributed K-split reduce + cell update (owner: tc == kh) ----
        #pragma unroll
        for (int tc = 0; tc < 4; ++tc)
            #pragma unroll
            for (int rf = 0; rf < 2; ++rf)
                *(f32x4*)&Xl[kh][cq][tc][rf][lane * 4] = acc[tc][rf];
        __syncthreads();
        #pragma unroll
        for (int rf = 0; rf < 2; ++rf) {
            f32x4 z = {0.f, 0.f, 0.f, 0.f};
            #pragma unroll
            for (int k2 = 0; k2 < 4; ++k2)
                z += *(const f32x4*)&Xl[k2][cq][kh][rf][lane * 4];
            const float zi = z[0] + biasq.x;
            const float zf = z[1] + biasq.y;
            const float zg = z[2] + biasq.z;
            const float zo = z[3] + biasq.w;
            const float cn = sigf(zf) * creg[rf] + sigf(zi) * tanh_fast(zg);
            creg[rf] = cn;
            // permuted local unit position: P(kh*4+lq) = lq*4+kh
            hTile[rf * 16 + lr][cq * 16 + lq * 4 + kh] = __float2bfloat16(sigf(zo) * tanh_fast(cn));
        }
        __syncthreads();

        // ---- store + publish by waves 6,7 (their chunks are consumed last next step) ----
        if (wave >= 6) {
            const int q = (wave - 6) * 64 + lane;     // 0..127
            const int row = q >> 2, ch = q & 3;
            *(i32x4*)(hdst + (size_t)(b0 + row) * 1024 + ublk + ch * 8) =
                *(const i32x4*)&hTile[row][ch * 8];
            VMCNT0;
            if (lane < 32) l2_atomic_inc(flag_at(lane, tile >> 2));
        }
        // x prefetch for t+1 (wave 0, unburdened; all compute passed the Xl sync)
        if (wave == 0 && t + 1 < 256) {
            #pragma unroll
            for (int j = 0; j < 8; ++j) {
                const int row = j * 4 + sr;
                const int ce = (scol ^ (row & 15)) << 3;
                gload_lds16(xb + (size_t)(b0 + row) * 32768 + (size_t)(t + 1) * 128 + ce,
                            (char*)&Als[0][0][0] + j * 1024);
            }
        }
    }
}

// ---------- final p-GEMM: out[b][t][f] = hist[t][b] @ W_d + b_d ----------
__global__ __launch_bounds__(256) void pgemm(char* ws, float* __restrict__ out,
                                             const float* __restrict__ bd) {
    const int t = blockIdx.x >> 2;
    const int r0 = (blockIdx.x & 3) * 64;
    const int f0 = blockIdx.y * 64;
    const __hip_bfloat16* A = hist_ptr(ws, t);
    const __hip_bfloat16* Bw = (const __hip_bfloat16*)(ws + OWD);

    __shared__ __hip_bfloat16 Al[2][64 * 64];
    __shared__ __hip_bfloat16 Bl[2][64 * 64];

    const int tid = threadIdx.x;
    const int wave = tid >> 6, lane = tid & 63;
    const int whb = (wave >> 1) * 32, wcf = (wave & 1) * 32;
    const int lr = lane & 15, lq = lane >> 4;
    const int l8 = lane >> 3, cb = lane & 7;
    const int gsw = ((cb ^ l8) << 3);
    const int xk = lr & 7;

    f32x4 acc[2][2] = {};
    const int rA0 = whb + lr, rA1 = whb + lr + 16;
    const int rB0 = wcf + lr, rB1 = wcf + lr + 16;

    auto stage = [&](int buf, int k0) {
        #pragma unroll
        for (int l = 0; l < 2; ++l) {
            const int rt = wave * 16 + l * 8;
            const int row = rt + l8;
            gload_lds16(A + (size_t)(r0 + row) * 1024 + k0 + gsw, &Al[buf][rt * 64]);
            gload_lds16(Bw + (size_t)(f0 + row) * 1024 + k0 + gsw, &Bl[buf][rt * 64]);
        }
    };

    stage(0, 0);
    for (int kk = 0; kk < 16; ++kk) {
        const int buf = kk & 1;
        if (kk + 1 < 16) { stage(buf ^ 1, (kk + 1) << 6); asm volatile("s_waitcnt vmcnt(4)" ::: "memory"); }
        else             { VMCNT0; }
        CFENCE; __builtin_amdgcn_s_barrier(); CFENCE;
        #pragma unroll
        for (int ks = 0; ks < 2; ++ks) {
            const int g0 = ((ks * 4 + lq) ^ xk) << 3;
            bf16x8 a0 = *(const bf16x8*)&Al[buf][rA0 * 64 + g0];
            bf16x8 a1 = *(const bf16x8*)&Al[buf][rA1 * 64 + g0];
            bf16x8 w0 = *(const bf16x8*)&Bl[buf][rB0 * 64 + g0];
            bf16x8 w1 = *(const bf16x8*)&Bl[buf][rB1 * 64 + g0];
            acc[0][0] = __builtin_amdgcn_mfma_f32_16x16x32_bf16(w0, a0, acc[0][0], 0, 0, 0);
            acc[0][1] = __builtin_amdgcn_mfma_f32_16x16x32_bf16(w0, a1, acc[0][1], 0, 0, 0);
            acc[1][0] = __builtin_amdgcn_mfma_f32_16x16x32_bf16(w1, a0, acc[1][0], 0, 0, 0);
            acc[1][1] = __builtin_amdgcn_mfma_f32_16x16x32_bf16(w1, a1, acc[1][1], 0, 0, 0);
        }
        CFENCE; __builtin_amdgcn_s_barrier(); CFENCE;
    }
    #pragma unroll
    for (int cf = 0; cf < 2; ++cf) {
        const int fb = f0 + wcf + cf * 16 + lq * 4;
        const float4 b4 = *(const float4*)(bd + fb);
        #pragma unroll
        for (int rf = 0; rf < 2; ++rf) {
            const int b = r0 + whb + rf * 16 + lr;
            float4 o;
            o.x = acc[cf][rf][0] + b4.x;
            o.y = acc[cf][rf][1] + b4.y;
            o.z = acc[cf][rf][2] + b4.z;
            o.w = acc[cf][rf][3] + b4.w;
            *(float4*)(out + (size_t)b * 16384 + (size_t)t * 128 + fb) = o;
        }
    }
}

// ---------- launcher ----------

extern "C" void kernel_launch(void* const* d_in, const int* in_sizes, int n_in,
                              void* d_out, int out_size, void* d_ws, size_t ws_size,
                              hipStream_t stream) {
    const float* inputs = (const float*)d_in[0];
    const float* W_i    = (const float*)d_in[1];
    const float* W_h    = (const float*)d_in[2];
    const float* b      = (const float*)d_in[3];
    const float* W_d    = (const float*)d_in[4];
    const float* b_d    = (const float*)d_in[5];
    float* out = (float*)d_out;
    char* ws = (char*)d_ws;

    (void)hipMemsetAsync(ws + OHP, 0, HSB, stream);        // h(0) = 0
    (void)hipMemsetAsync(ws + OCNT, 0, 262400, stream);    // flags + slotc + global counter

    cvt_bf16<<<8192, 256, 0, stream>>>(inputs, (__hip_bfloat16*)(ws + OX), 256 * 256 * 128);
    build_whwi<<<(1152 * 4096) / 256, 256, 0, stream>>>(
        W_h, W_i, (__hip_bfloat16*)(ws + OWH), (__hip_bfloat16*)(ws + OWI));
    build_wd<<<(128 * 1024) / 256, 256, 0, stream>>>(W_d, (__hip_bfloat16*)(ws + OWD));
    build_bias<<<16, 256, 0, stream>>>(b, b_d, W_i, (float*)(ws + OBR), (float*)(ws + OBF));
    build_wf<<<dim3(64, 16), 256, 0, stream>>>(
        (const __hip_bfloat16*)(ws + OWH), (const __hip_bfloat16*)(ws + OWI),
        W_d, (__hip_bfloat16*)(ws + OWF));

    char* wsp = ws;
    void* ka[] = { &wsp };
    (void)hipLaunchCooperativeKernel((void*)persist, dim3(256), dim3(512), ka, 0, stream);

    pgemm<<<dim3(512, 2), 256, 0, stream>>>(ws, out, b_d);
}